// Round 5
// baseline (2916.686 us; speedup 1.0000x reference)
//
#include <hip/hip_runtime.h>
#include <cstdint>
#include <cstddef>

// Problem constants
#define NB    64      // batch
#define NS    4096    // seq len
#define NH    1024    // hidden
#define NOPSN 8
#define NSTEP 10

#define GRID  256
#define TPB   1024    // 16 waves/block, 1 block/CU -> 4 waves/SIMD

// Workspace layout (float offsets), ~5.5 MB. Normal cached stores + fenced
// grid barrier (R3-proven). Weights live in VGPRs across all steps.
#define OFF_HN   0u          // hn  [64][1024]
#define OFF_HNT  65536u      // hnT [512][128] (k-pair interleave)
#define OFF_H    131072u     // h   [64][1024] (block-private in phase D)
#define OFF_CAND 196608u     // cand [64][256] float2 (val, idx)
#define OFF_OPP  229376u     // opp [10][16 jg][64 b][8 o]
#define OFF_PC   311296u     // pc  [16 kg][16 jg][64 b][64 j]  (4 MB)
#define OFF_CTRL 1359872u    // ints: [0]=magic [1]=barrier cnt [2..11]=stopcnt[t]
#define MAGIC    0x1357A5E5

typedef float f2v  __attribute__((ext_vector_type(2)));
typedef float f4v  __attribute__((ext_vector_type(4)));
typedef float f16v __attribute__((ext_vector_type(16)));

__device__ __forceinline__ float bcastf(float v, int l) {
  return __int_as_float(__builtin_amdgcn_readlane(__float_as_int(v), l));
}

// Device-scope grid barrier with full fences (R3-verified).
__device__ __forceinline__ void gridbar(int* cnt, int target) {
  __syncthreads();
  if (threadIdx.x == 0) {
    __threadfence();  // release (device scope)
    __hip_atomic_fetch_add(cnt, 1, __ATOMIC_RELAXED, __HIP_MEMORY_SCOPE_AGENT);
    while (__hip_atomic_load(cnt, __ATOMIC_RELAXED, __HIP_MEMORY_SCOPE_AGENT) < target)
      __builtin_amdgcn_s_sleep(1);
    __threadfence();  // acquire
  }
  __syncthreads();
}

__global__ void __launch_bounds__(TPB, 4)
sys1_kernel(const float* __restrict__ s2a,  const float* __restrict__ Wres,
            const float* __restrict__ bres, const float* __restrict__ Wop,
            const float* __restrict__ bop,  const float* __restrict__ Wx,
            const float* __restrict__ bx,   const float* __restrict__ noise,
            float* __restrict__ out,        float* __restrict__ wsf)
{
  __shared__ float smem[16384];   // 64 KB

  float* __restrict__ hn  = wsf + OFF_HN;
  float* __restrict__ hnT = wsf + OFF_HNT;
  float* __restrict__ h   = wsf + OFF_H;
  float* __restrict__ opp = wsf + OFF_OPP;
  float* __restrict__ pc  = wsf + OFF_PC;
  int* ctrl = (int*)(wsf + OFF_CTRL);
  int* cnt  = ctrl + 1;

  const int tid = threadIdx.x;
  const int blk = blockIdx.x;

  // ---- bootstrap: block 0 inits ctrl (ws is poisoned every launch) ----
  if (blk == 0 && tid == 0) {
    #pragma unroll
    for (int i = 1; i < 32; ++i) ctrl[i] = 0;
    __threadfence();
    __hip_atomic_store(&ctrl[0], (int)MAGIC, __ATOMIC_RELEASE, __HIP_MEMORY_SCOPE_AGENT);
  }
  if (tid == 0) {
    while (__hip_atomic_load(&ctrl[0], __ATOMIC_RELAXED, __HIP_MEMORY_SCOPE_AGENT) != (int)MAGIC)
      __builtin_amdgcn_s_sleep(1);
  }
  __syncthreads();

  const int lane = tid & 63;
  const int wv   = __builtin_amdgcn_readfirstlane(tid >> 6);   // wave 0..15

  // ---- persistent weight registers (loaded ONCE, survive all fences) ----
  // Phase A: lane l holds Wx[wv*64 + l][s0A..s0A+15]  (16 VGPRs)
  const int s0A = blk << 4;
  const int kbaseA = wv << 6;
  const f16v wreg = *(const f16v*)(Wx + (size_t)(kbaseA + lane) * NS + s0A);
  // Phase C: block = (jgC: 64 j, kgC: 128 k); wave owns 8 k; lane = j. (8 VGPRs)
  const int jgC = blk & 15, kgC = blk >> 4;
  const int j0C = jgC << 6, k0C = kgC << 7;
  float wcr[8];
  #pragma unroll
  for (int i = 0; i < 8; ++i)
    wcr[i] = Wres[(size_t)(k0C + (wv << 3) + i) * NH + j0C + lane];

  // ---- INIT: hn(0)=0.01*noise[0], hnT(0), h=0, opp[0] ----
  {
    const int jg = blk & 15, bg = blk >> 4;
    if (tid < 256) {
      const int bsel = tid >> 6, jloc = tid & 63;
      const int b = bg * 4 + bsel, j = jg * 64 + jloc;
      float hv = 0.01f * noise[(size_t)b * NH + j];
      hn[(size_t)b * NH + j] = hv;
      hnT[((size_t)(j >> 1)) * 128 + b * 2 + (j & 1)] = hv;
      h[(size_t)b * NH + j] = 0.f;
      const float* wr = Wop + (size_t)j * NOPSN;
      float opo[8];
      #pragma unroll
      for (int o = 0; o < 8; ++o) opo[o] = hv * wr[o];
      #pragma unroll
      for (int off = 1; off <= 32; off <<= 1) {
        #pragma unroll
        for (int o = 0; o < 8; ++o) opo[o] += __shfl_xor(opo[o], off);
      }
      if ((tid & 63) == 0) {
        float* od = opp + (size_t)jg * 512 + (size_t)b * 8;
        #pragma unroll
        for (int o = 0; o < 8; ++o) od[o] = opo[o];
      }
    }
  }
  int ep = 0;
  gridbar(cnt, ++ep * GRID);

  for (int st = 0; st < NSTEP; ++st) {

    // ================= PHASE A =================
    // Block: x_logits[16 s][64 b], full K=1024. lane = b. Weights in VGPRs,
    // broadcast per (k,s) via readlane; h from hnT (per-lane float2).
    {
      const float2* hb = (const float2*)hnT + ((size_t)(kbaseA >> 1)) * 64 + lane;
      float2 hA[8], hB[8];
      #pragma unroll
      for (int i = 0; i < 8; ++i) hA[i] = hb[(size_t)i * 64];
      #pragma unroll
      for (int i = 0; i < 8; ++i) hB[i] = hb[(size_t)(8 + i) * 64];

      // op-argmax for step st (blocks 0..63, wave 0) — overlaps the loads
      if (blk < NB && tid < 64) {
        const float* ob = opp + (size_t)st * 8192 + (size_t)blk * 8;
        const int o = lane & 7, jgb = lane >> 3;
        float v = ob[(size_t)jgb * 512 + o] + ob[(size_t)(jgb + 8) * 512 + o];
        v += __shfl_xor(v, 8);
        v += __shfl_xor(v, 16);
        v += __shfl_xor(v, 32);
        v += bop[o];
        float bv = bcastf(v, 0); int bo = 0;
        #pragma unroll
        for (int oo = 1; oo < 8; ++oo) {
          float vo = bcastf(v, oo);
          if (vo > bv) { bv = vo; bo = oo; }        // strict > : first-max
        }
        if (lane == 0 && bo == 0) atomicAdd(&ctrl[2 + st], 1);
      }

      f2v acc[8];
      #pragma unroll
      for (int i = 0; i < 8; ++i) acc[i] = (f2v){0.f, 0.f};

#define CHUNKA(HREG, KP0)                                                   \
      _Pragma("unroll")                                                     \
      for (int i = 0; i < 8; ++i) {                                         \
        const float2 hc = HREG[i];                                          \
        _Pragma("unroll")                                                   \
        for (int s = 0; s < 8; ++s) {                                       \
          f2v w0 = { bcastf(wreg[2*s], 2*((KP0)+i)),                        \
                     bcastf(wreg[2*s+1], 2*((KP0)+i)) };                    \
          f2v w1 = { bcastf(wreg[2*s], 2*((KP0)+i)+1),                      \
                     bcastf(wreg[2*s+1], 2*((KP0)+i)+1) };                  \
          acc[s] += w0 * hc.x;                                              \
          acc[s] += w1 * hc.y;                                              \
        }                                                                   \
      }

      CHUNKA(hA, 0)
      #pragma unroll
      for (int i = 0; i < 8; ++i) hA[i] = hb[(size_t)(16 + i) * 64];
      CHUNKA(hB, 8)
      #pragma unroll
      for (int i = 0; i < 8; ++i) hB[i] = hb[(size_t)(24 + i) * 64];
      CHUNKA(hA, 16)
      CHUNKA(hB, 24)
#undef CHUNKA

      // cross-wave K reduction: red[16 w][16 s][64 b]
      #pragma unroll
      for (int s = 0; s < 8; ++s) {
        smem[wv * 1024 + (2 * s) * 64 + lane]     = acc[s].x;
        smem[wv * 1024 + (2 * s + 1) * 64 + lane] = acc[s].y;
      }
      __syncthreads();
      {
        const int s = tid >> 6, b = tid & 63;
        float val = bx[s0A + s];
        #pragma unroll
        for (int w = 0; w < 16; ++w) val += smem[w * 1024 + s * 64 + b];
        __syncthreads();
        smem[s * 64 + b] = val;
        __syncthreads();
        if (tid < 64) {
          const int bb = tid;
          float bv = smem[bb]; int bs = 0;
          #pragma unroll
          for (int s2 = 1; s2 < 16; ++s2) {
            float v2 = smem[s2 * 64 + bb];
            if (v2 > bv) { bv = v2; bs = s2; }      // ascending s: first-max
          }
          float2* cp = (float2*)(wsf + OFF_CAND);
          cp[bb * 256 + blk] = make_float2(bv, __int_as_float(s0A + bs));
        }
      }
    }
    gridbar(cnt, ++ep * GRID);

    // ================= PHASE C =================
    // Block (jgC, kgC): partial over its [128 k x 64 j] register tile for
    // all 64 b (two passes of 32). h gathered per-lane (1 load/pass),
    // broadcast via readlane. Cross-wave reduce via LDS atomic add.
    {
      int* ptrSm = (int*)(smem + 8192);
      if (kgC >= 8) {                               // s2a half needs ptrs
        const float2* cp = (const float2*)(wsf + OFF_CAND);
        const int b0r = wv << 2;
        #pragma unroll
        for (int i = 0; i < 4; ++i) {
          const float2* row = cp + (size_t)(b0r + i) * 256;
          float2 c0 = row[lane];
          float bv = c0.x; int bi = __float_as_int(c0.y);
          #pragma unroll
          for (int q = 1; q < 4; ++q) {
            float2 c = row[q * 64 + lane];
            if (c.x > bv) { bv = c.x; bi = __float_as_int(c.y); }
          }
          #pragma unroll
          for (int off = 1; off <= 32; off <<= 1) {
            float ov = __shfl_xor(bv, off);
            int   oi = __shfl_xor(bi, off);
            if (ov > bv || (ov == bv && oi < bi)) { bv = ov; bi = oi; }
          }
          if (lane == 0) ptrSm[b0r + i] = bi;
        }
      }
      // zero the 4096-float accumulation region
      ((f4v*)smem)[tid] = (f4v){0.f, 0.f, 0.f, 0.f};
      __syncthreads();

      const int bl = lane >> 1, half = lane & 1;
      const int ksub = k0C + (wv << 3) + (half << 2);
      const float *s0p, *s1p;
      if (kgC < 8) {
        s0p = hn + (size_t)bl * NH + ksub;
        s1p = hn + (size_t)(32 + bl) * NH + ksub;
      } else {
        int pA = ptrSm[bl], pB = ptrSm[32 + bl];
        s0p = s2a + ((size_t)bl * NS + pA) * NH + (ksub - NH);
        s1p = s2a + ((size_t)(32 + bl) * NS + pB) * NH + (ksub - NH);
      }
      f4v hr0 = *(const f4v*)s0p;
      f4v hr1 = *(const f4v*)s1p;

      {
        float acc[32];
        #pragma unroll
        for (int b = 0; b < 32; ++b) acc[b] = 0.f;
        #pragma unroll
        for (int b = 0; b < 32; ++b) {
          #pragma unroll
          for (int k = 0; k < 8; ++k)
            acc[b] += bcastf(hr0[k & 3], 2 * b + (k >> 2)) * wcr[k];
        }
        #pragma unroll
        for (int b = 0; b < 32; ++b) atomicAdd(&smem[b * 64 + lane], acc[b]);
      }
      {
        float acc[32];
        #pragma unroll
        for (int b = 0; b < 32; ++b) acc[b] = 0.f;
        #pragma unroll
        for (int b = 0; b < 32; ++b) {
          #pragma unroll
          for (int k = 0; k < 8; ++k)
            acc[b] += bcastf(hr1[k & 3], 2 * b + (k >> 2)) * wcr[k];
        }
        #pragma unroll
        for (int b = 0; b < 32; ++b) atomicAdd(&smem[2048 + b * 64 + lane], acc[b]);
      }
      __syncthreads();
      // write block's pc tile: [64 b][64 j] contiguous 16 KB
      {
        f4v v = ((const f4v*)smem)[tid];
        ((f4v*)(pc + (size_t)(kgC * 16 + jgC) * 4096))[tid] = v;
      }
    }
    gridbar(cnt, ++ep * GRID);

    // ================= PHASE D =================
    // Block (jg, bg): reduce 16 kg-partials for [4 b x 64 j], freeze logic,
    // next h_n + opp epilogue (R3-verified).
    {
      const int jg = blk & 15, bg = blk >> 4;
      const int j0 = jg << 6, b0 = bg << 2;
      const int q = tid >> 8, idx = tid & 255;
      {
        const int bsel = idx >> 6, jloc = idx & 63;
        float s = 0.f;
        #pragma unroll
        for (int kk = 0; kk < 4; ++kk) {
          const int kg = q * 4 + kk;
          s += pc[((size_t)(kg * 16 + jg) * 64 + (b0 + bsel)) * 64 + jloc];
        }
        smem[q * 256 + idx] = s;
      }
      __syncthreads();

      if (tid < 256) {
        const int bsel = tid >> 6, jloc = tid & 63;
        float v = bres[j0 + jloc] + smem[tid] + smem[256 + tid]
                + smem[512 + tid] + smem[768 + tid];
        int done = 0;
        for (int tt = 0; tt < st; ++tt) done |= (ctrl[2 + tt] == NB) ? 1 : 0;
        const int b = b0 + bsel, j = j0 + jloc;
        float hold = h[(size_t)b * NH + j];
        float hout = done ? hold : v;
        h[(size_t)b * NH + j] = hout;
        if (st < NSTEP - 1) {
          float hnv = hout + 0.01f * noise[(size_t)(st + 1) * (NB * NH) + (size_t)b * NH + j];
          hn[(size_t)b * NH + j] = hnv;
          hnT[((size_t)(j >> 1)) * 128 + b * 2 + (j & 1)] = hnv;
          const float* wr = Wop + (size_t)j * NOPSN;
          float opo[8];
          #pragma unroll
          for (int o = 0; o < 8; ++o) opo[o] = hnv * wr[o];
          #pragma unroll
          for (int off = 1; off <= 32; off <<= 1) {
            #pragma unroll
            for (int o = 0; o < 8; ++o) opo[o] += __shfl_xor(opo[o], off);
          }
          if ((tid & 63) == 0) {
            float* od = opp + ((size_t)(st + 1) * 16 + jg) * 512 + (size_t)b * 8;
            #pragma unroll
            for (int o = 0; o < 8; ++o) od[o] = opo[o];
          }
        } else {
          out[(size_t)b * NH + j] = hout;
        }
      }
    }
    if (st < NSTEP - 1) gridbar(cnt, ++ep * GRID);
  }
}

extern "C" void kernel_launch(void* const* d_in, const int* in_sizes, int n_in,
                              void* d_out, int out_size, void* d_ws, size_t ws_size,
                              hipStream_t stream) {
  const float* s2a   = (const float*)d_in[0];
  const float* Wres  = (const float*)d_in[1];
  const float* bres  = (const float*)d_in[2];
  const float* Wop   = (const float*)d_in[3];
  const float* bop   = (const float*)d_in[4];
  const float* Wx    = (const float*)d_in[5];
  const float* bx    = (const float*)d_in[6];
  const float* noise = (const float*)d_in[7];
  float* outp = (float*)d_out;
  float* wsf  = (float*)d_ws;   // needs ~5.5 MB
  hipLaunchKernelGGL(sys1_kernel, dim3(GRID), dim3(TPB), 0, stream,
                     s2a, Wres, bres, Wop, bop, Wx, bx, noise, outp, wsf);
}